// Round 12
// baseline (81.162 us; speedup 1.0000x reference)
//
#include <hip/hip_runtime.h>
#include <hip/hip_bf16.h>
#include <math.h>

// signs c1,c2 decoded in round 0/1: both +1 (absmax 0.0078 = bf16 noise)
#define C1 1.0f
#define C2 1.0f

static constexpr float EPSF = 1e-8f;
static constexpr int NIN = 1024;
static constexpr int NH  = 2048;
static constexpr int NU  = NIN + NH + 1;   // 3073

typedef __attribute__((ext_vector_type(8))) short bf16x8;
typedef __attribute__((ext_vector_type(4))) float f32x4;

// ws layout (bytes) -- MUST stay <= 16809984 (round-1 proven ws budget):
//   0       dh    2048 f32 (8 KiB)
//   8192    dhp   8 f32
//   8256    gp    1024 f32 (4 KiB, gemm grid partials)
//   12352   nrm   3 f32
//   16384   Abf   2048*2048 bf16 (8 MiB) = dh[m]*W_h[m][k]
//   8404992 Bt    2048*2048 bf16 (8 MiB) = A_prev^T
//   end 16793600
// z-partials (32*2048 f32, 256 KiB) live in d_out's A_next region (dead until k_gemm).
//
// LESSON (r8-r10): agent-scope ordered atomics inside k_gemm force L2
// writeback/invalidate -> co-resident blocks' panels evicted -> gemm 33->104us.
// NO atomics anywhere.
// LESSON (r11): per-iteration `if (hprev[i]!=0)` before the Wh row load made
// each row a load->waitcnt->branch serial chain (stage1 -> 50us, VALUBusy 1.4%).
// Fix: batch-prefetch coefficients to LDS, branch on LDS value (wave-uniform),
// let surviving row loads stream.

__device__ inline unsigned short f2bf(float f) {
  union { float f; unsigned u; } v; v.f = f;
  unsigned r = v.u + 0x7FFFu + ((v.u >> 16) & 1u);   // RNE
  return (unsigned short)(r >> 16);
}

__device__ inline float blockReduce256(float v, float* red) {
  int t = threadIdx.x;
  red[t] = v;
  __syncthreads();
  for (int s = 128; s > 0; s >>= 1) {
    if (t < s) red[t] += red[t + s];
    __syncthreads();
  }
  float r = red[0];
  __syncthreads();
  return r;
}

// fused stage 1 (no z-dependency):
//   blocks [0,256)     : z partials (8 j-blocks x 32 i-slices of 96 rows);
//                        coefficients (x / h_prev) prefetched to LDS in
//                        parallel, then rows with zero h_prev coefficient are
//                        skipped via a cheap uniform branch (saves the 16MB
//                        W_h read without a serial load-branch chain)
//   blocks [256,1280)  : Bt[n][k] = bf16(A_prev[k][n]) 64x64 tiled transpose
//   block  1280        : norms (sumsq u, x, h_prev)
__global__ void k_stage1(const float* __restrict__ x, const float* __restrict__ hprev,
                         const float* __restrict__ Win, const float* __restrict__ Wh,
                         float* __restrict__ part,
                         const float* __restrict__ Ap, unsigned short* __restrict__ Bt,
                         const float* __restrict__ u, float* __restrict__ nrm) {
  __shared__ float ls[64][65];
  __shared__ float hl[96];
  int b = blockIdx.x;
  int t = threadIdx.x;
  if (b < 256) {
    int bj = b & 7, bi = b >> 3;
    int j = bj * 256 + t;
    int i0 = bi * 96;                   // 32*96 == 3072 == NIN+NH exactly
    if (t < 96) {
      int i = i0 + t;
      hl[t] = (i < NIN) ? x[i] : hprev[i - NIN];   // 96 parallel loads
    }
    __syncthreads();
    float s = 0.f;
    for (int ii = 0; ii < 96; ++ii) {
      int i = i0 + ii;
      float cv = hl[ii];                // LDS-resident; block-uniform branch
      if (i < NIN) {
        s += cv * Win[(size_t)i * NH + j];
      } else if (cv != 0.0f) {
        s += cv * Wh[(size_t)(i - NIN) * NH + j];
      }
    }
    part[bi * NH + j] = s;
  } else if (b < 1280) {
    int bb = b - 256;
    int tn = bb & 31, tk = bb >> 5;
    int r = t >> 4, c = (t & 15) * 4;
#pragma unroll
    for (int i = 0; i < 4; ++i) {
      float4 v = *(const float4*)&Ap[(size_t)(tk * 64 + r + i * 16) * NH + tn * 64 + c];
      ls[r + i * 16][c] = v.x; ls[r + i * 16][c + 1] = v.y;
      ls[r + i * 16][c + 2] = v.z; ls[r + i * 16][c + 3] = v.w;
    }
    __syncthreads();
#pragma unroll
    for (int i = 0; i < 4; ++i) {
      int n = r + i * 16;
      ushort4 o;
      o.x = f2bf(ls[c][n]);     o.y = f2bf(ls[c + 1][n]);
      o.z = f2bf(ls[c + 2][n]); o.w = f2bf(ls[c + 3][n]);
      *(ushort4*)&Bt[(size_t)(tn * 64 + n) * NH + tk * 64 + c] = o;
    }
  } else {
    float* red = (float*)ls;
    float su = 0, sx = 0, sh = 0;
    for (int i = t; i < NU;  i += 256) su += u[i] * u[i];
    for (int i = t; i < NIN; i += 256) sx += x[i] * x[i];
    for (int i = t; i < NH;  i += 256) sh += hprev[i] * hprev[i];
    float r0 = blockReduce256(su, red);
    float r1 = blockReduce256(sx, red);
    float r2 = blockReduce256(sh, red);
    if (t == 0) { nrm[0] = r0; nrm[1] = r1; nrm[2] = r2; }
  }
}

// fused: blocks [0,4096): Abf[m][k] = bf16(dh[m]*W_h[m][k]) with dh recomputed
// per block from z-partials; blocks [4096,4104): z2 epilogue (h_next, dh, dhp).
__global__ void k_prep(const float* __restrict__ Wh, const float* __restrict__ part,
                       const float* __restrict__ bias,
                       unsigned short* __restrict__ Abf,
                       float* __restrict__ outh, float* __restrict__ dh,
                       float* __restrict__ dhp) {
  __shared__ float red[256];
  __shared__ float dhs;
  int b = blockIdx.x, t = threadIdx.x;
  if (b < 4096) {
    int r = b >> 1;                       // 256 float4 per block = half a 512-float4 row
    if (t < 32) red[t] = part[t * NH + r];
    __syncthreads();
    if (t == 0) {
      float z = bias[r];
      for (int i = 0; i < 32; ++i) z += red[i];
      float h = tanhf(z);
      dhs = 1.f - h * h;
    }
    __syncthreads();
    float d = dhs;
    int idx4 = b * 256 + t;               // 4096*256 == 2^20 == Wh/4 exactly
    float4 w = ((const float4*)Wh)[idx4];
    ushort4 o;
    o.x = f2bf(w.x * d); o.y = f2bf(w.y * d);
    o.z = f2bf(w.z * d); o.w = f2bf(w.w * d);
    ((ushort4*)Abf)[idx4] = o;
  } else {
    int j = (b - 4096) * 256 + t;
    float z = bias[j];
    for (int bi = 0; bi < 32; ++bi) z += part[bi * NH + j];
    float h = tanhf(z);
    outh[j] = h;
    float d = 1.f - h * h;
    dh[j] = d;
    float s = blockReduce256(d * d, red);
    if (t == 0) dhp[b - 4096] = s;
  }
}

#define GLOAD_LDS(gsrc, ldst) \
  __builtin_amdgcn_global_load_lds( \
      (const __attribute__((address_space(1))) unsigned int*)(gsrc), \
      (__attribute__((address_space(3))) unsigned int*)(ldst), 16, 0, 0)

// C[m][n] = sum_k Abf[m][k]*Bt[n][k] (= H @ A_prev), writes Hq f32 + sumsq gp.
// PROVEN CORE, byte-identical to the 62.3us config: 64x64 tile, BK=64, 4 waves,
// wave subtile 32x32 (acc[2][2], 8 MFMA/step), 32 stage->drain->compute iters;
// LDS [row][kg] granules XOR'd kg^(row&7) both-sides (0 conflicts measured).
// Grid 1024 -> 4 blocks/CU. Plain stores only -- NO atomics.
__global__ __launch_bounds__(256) void k_gemm(const unsigned short* __restrict__ Abf,
                                              const unsigned short* __restrict__ Bt,
                                              float* __restrict__ Hq,
                                              float* __restrict__ gp) {
  __shared__ unsigned short As[512 * 8];   // 64 rows x 8 granules x 16B = 8KB
  __shared__ unsigned short Bs[512 * 8];
  __shared__ float red[256];
  const int K = NH;
  int t = threadIdx.x;
  int lane = t & 63;
  int bm = blockIdx.x >> 5, bn = blockIdx.x & 31;
  int wid = t >> 6;
  int wr = wid >> 1, wc = wid & 1;

  int srow = t >> 3, skg = t & 7;
  int sxg = skg ^ (srow & 7);
  const unsigned short* AgBase = Abf + (size_t)(bm * 64 + srow) * K + sxg * 8;
  const unsigned short* BgBase = Bt  + (size_t)(bn * 64 + srow) * K + sxg * 8;

  f32x4 acc[2][2] = {};

  for (int k0 = 0; k0 < K; k0 += 64) {
    GLOAD_LDS(AgBase + k0,          As + t * 8);
    GLOAD_LDS(AgBase + 32 * K + k0, As + (t + 256) * 8);
    GLOAD_LDS(BgBase + k0,          Bs + t * 8);
    GLOAD_LDS(BgBase + 32 * K + k0, Bs + (t + 256) * 8);
    __syncthreads();
    __builtin_amdgcn_s_setprio(1);
#pragma unroll
    for (int kk = 0; kk < 2; ++kk) {
      bf16x8 af[2], bfr[2];
#pragma unroll
      for (int mi = 0; mi < 2; ++mi) {
        int row = wr * 32 + mi * 16 + (lane & 15);
        int kg = (kk * 4 + (lane >> 4)) ^ (row & 7);
        af[mi] = *(const bf16x8*)&As[(row * 8 + kg) * 8];
      }
#pragma unroll
      for (int ni = 0; ni < 2; ++ni) {
        int row = wc * 32 + ni * 16 + (lane & 15);
        int kg = (kk * 4 + (lane >> 4)) ^ (row & 7);
        bfr[ni] = *(const bf16x8*)&Bs[(row * 8 + kg) * 8];
      }
#pragma unroll
      for (int mi = 0; mi < 2; ++mi)
#pragma unroll
        for (int ni = 0; ni < 2; ++ni)
          acc[mi][ni] = __builtin_amdgcn_mfma_f32_16x16x32_bf16(af[mi], bfr[ni], acc[mi][ni], 0, 0, 0);
    }
    __builtin_amdgcn_s_setprio(0);
    __syncthreads();
  }

  float ss = 0.f;
  int r0 = bm * 64 + wr * 32 + (lane >> 4) * 4;
  int c0 = bn * 64 + wc * 32 + (lane & 15);
#pragma unroll
  for (int mi = 0; mi < 2; ++mi)
#pragma unroll
    for (int r = 0; r < 4; ++r) {
      int row = r0 + mi * 16 + r;
#pragma unroll
      for (int ni = 0; ni < 2; ++ni) {
        float v = acc[mi][ni][r];
        Hq[(size_t)row * NH + c0 + ni * 16] = v;
        ss += v * v;
      }
    }
  float s = blockReduce256(ss, red);
  if (t == 0) gp[blockIdx.x] = s;
}

// blocks [0,2048): A_next = cf2*Hq (+ diag cf3*dh) in place, float4.
// blocks [2048,2061): u_next.
// Every block re-reduces gp[1024] + dhp + nrm and computes coef inline
// (identical fixed-order arithmetic per block -> deterministic; L2-hot).
__global__ void k_Au(float* __restrict__ Hq, const float* __restrict__ dh,
                     const float* __restrict__ gp, const float* __restrict__ dhp,
                     const float* __restrict__ nrm,
                     const float* __restrict__ u, const float* __restrict__ x,
                     const float* __restrict__ hprev, float* __restrict__ outu) {
  __shared__ float red[256];
  __shared__ float cf[4];
  int t = threadIdx.x;
  float s = blockReduce256(gp[t] + gp[t + 256] + gp[t + 512] + gp[t + 768], red);
  if (t == 0) {
    float sdh = 0;
    for (int i = 0; i < 8; ++i) sdh += dhp[i];
    float nu  = sqrtf(nrm[0]);
    float nhq = sqrtf(nrm[1] + nrm[2] + 1.0f);
    float ndh = sqrtf(sdh);
    float nHq = sqrtf(s);
    float p1 = sqrtf(nHq / (EPSF + nu));
    float p2 = sqrtf(ndh / (EPSF + nhq));
    cf[0] = C1 * p1;
    cf[1] = C2 * p2;
    cf[2] = C1 / (p1 + EPSF);
    cf[3] = C2 / (p2 + EPSF);
  }
  __syncthreads();

  if (blockIdx.x >= 2048) {
    int i = (blockIdx.x - 2048) * 256 + t;
    if (i < NU) {
      float hq = (i < NIN) ? x[i] : (i < NIN + NH ? hprev[i - NIN] : 1.0f);
      outu[i] = cf[0] * u[i] + cf[1] * hq;
    }
    return;
  }
  float sA = cf[2], sD = cf[3];
  float4* H4 = (float4*)Hq;
  // 2048 blocks * 256 thr * 2 iters == 2^20 float4 == NH*NH/4 exactly
  int i4 = blockIdx.x * 256 + t;
#pragma unroll
  for (int it = 0; it < 2; ++it, i4 += 2048 * 256) {
    float4 v = H4[i4];
    v.x *= sA; v.y *= sA; v.z *= sA; v.w *= sA;
    int row = i4 >> 9;                 // 512 float4 per row
    int c = (i4 & 511) * 4;
    int j = row - c;
    if (j >= 0 && j < 4) {
      float add = sD * dh[row];
      if (j == 0) v.x += add; else if (j == 1) v.y += add;
      else if (j == 2) v.z += add; else v.w += add;
    }
    H4[i4] = v;
  }
}

extern "C" void kernel_launch(void* const* d_in, const int* in_sizes, int n_in,
                              void* d_out, int out_size, void* d_ws, size_t ws_size,
                              hipStream_t stream) {
  const float* x     = (const float*)d_in[0];
  const float* hprev = (const float*)d_in[1];
  const float* Win   = (const float*)d_in[2];
  const float* Wh    = (const float*)d_in[3];
  const float* bias  = (const float*)d_in[4];
  const float* uprev = (const float*)d_in[5];
  const float* Ap    = (const float*)d_in[6];

  float* out  = (float*)d_out;
  float* outh = out;                 // [2048]
  float* outu = out + NH;            // [3073]
  float* Hq   = out + NH + NU;       // [2048*2048] (in-place scaled to A_next)
  float* part = Hq;                  // z-partials borrow region (dead until k_gemm)

  char* ws = (char*)d_ws;
  float* dh   = (float*)ws;
  float* dhp  = (float*)(ws + 8192);
  float* gp   = (float*)(ws + 8256);
  float* nrm  = (float*)(ws + 12352);
  unsigned short* Abf = (unsigned short*)(ws + 16384);
  unsigned short* Bt  = (unsigned short*)(ws + 8404992);

  k_stage1 <<<1281, 256, 0, stream>>>(x, hprev, Win, Wh, part, Ap, Bt, uprev, nrm);
  k_prep   <<<4104, 256, 0, stream>>>(Wh, part, bias, Abf, outh, dh, dhp);
  k_gemm   <<<1024, 256, 0, stream>>>(Abf, Bt, Hq, gp);
  k_Au     <<<2061, 256, 0, stream>>>(Hq, dh, gp, dhp, nrm, uprev, x, hprev, outu);
}

// Round 13
// 65.306 us; speedup vs baseline: 1.2428x; 1.2428x over previous
//
#include <hip/hip_runtime.h>
#include <hip/hip_bf16.h>
#include <math.h>

// signs c1,c2 decoded in round 0/1: both +1 (absmax 0.0078 = bf16 noise)
#define C1 1.0f
#define C2 1.0f

static constexpr float EPSF = 1e-8f;
static constexpr int NIN = 1024;
static constexpr int NH  = 2048;
static constexpr int NU  = NIN + NH + 1;   // 3073

typedef __attribute__((ext_vector_type(8))) short bf16x8;
typedef __attribute__((ext_vector_type(4))) float f32x4;

// ws layout (bytes) -- MUST stay <= 16809984 (round-1 proven ws budget):
//   0       dh    2048 f32 (8 KiB)
//   8192    dhp   8 f32
//   8256    gp    1024 f32 (4 KiB, gemm grid partials)
//   12352   nrm   3 f32
//   16384   Abf   2048*2048 bf16 (8 MiB) = dh[m]*W_h[m][k]
//   8404992 Bt    2048*2048 bf16 (8 MiB) = A_prev^T
//   end 16793600
// z-partials (64*2048 f32, 512 KiB) live in d_out's A_next region (dead until k_gemm).
//
// LESSON (r8-r10): agent-scope ordered atomics inside k_gemm force L2
// writeback/invalidate -> panels evicted -> gemm 33->104us. NO atomics.
// LESSON (r11-r12): a LOAD inside a data-dependent branch (h_prev!=0 skip)
// can't be speculated/pipelined by LLVM -> serial check->load->wait chain,
// stage1 50us @ VALUBusy 1.7%. Fix: branch selects (coef, pointer) only;
// the float4 load itself is unconditional -> if-converted + pipelined.

__device__ inline unsigned short f2bf(float f) {
  union { float f; unsigned u; } v; v.f = f;
  unsigned r = v.u + 0x7FFFu + ((v.u >> 16) & 1u);   // RNE
  return (unsigned short)(r >> 16);
}

__device__ inline float blockReduce256(float v, float* red) {
  int t = threadIdx.x;
  red[t] = v;
  __syncthreads();
  for (int s = 128; s > 0; s >>= 1) {
    if (t < s) red[t] += red[t + s];
    __syncthreads();
  }
  float r = red[0];
  __syncthreads();
  return r;
}

// fused stage 1 (no z-dependency):
//   blocks [0,128)     : z partials, float4: 64 i-slices (48 rows) x 2 j-halves;
//                        thread owns one float4 col-group; coef prefetched to
//                        LDS; load unconditional (pointer selected by branch)
//   blocks [128,1152)  : Bt[n][k] = bf16(A_prev[k][n]) 64x64 tiled transpose
//   block  1152        : norms (sumsq u, x, h_prev)
__global__ void k_stage1(const float* __restrict__ x, const float* __restrict__ hprev,
                         const float* __restrict__ Win, const float* __restrict__ Wh,
                         float* __restrict__ part,
                         const float* __restrict__ Ap, unsigned short* __restrict__ Bt,
                         const float* __restrict__ u, float* __restrict__ nrm) {
  __shared__ float ls[64][65];
  __shared__ float hl[48];
  int b = blockIdx.x;
  int t = threadIdx.x;
  if (b < 128) {
    int bj = b & 1, bi = b >> 1;
    int jc4 = bj * 256 + t;             // float4 column-group (0..511)
    int i0 = bi * 48;                   // 64*48 == 3072 == NIN+NH exactly
    if (t < 48) {
      int i = i0 + t;
      hl[t] = (i < NIN) ? x[i] : hprev[i - NIN];   // 48 parallel loads
    }
    __syncthreads();
    float4 s = {0.f, 0.f, 0.f, 0.f};
    for (int ii = 0; ii < 48; ++ii) {
      int i = i0 + ii;
      // branch selects pointer only; the load below is UNCONDITIONAL
      const float4* wrow = (i < NIN)
        ? (const float4*)Win + (size_t)i * 512
        : (const float4*)Wh  + (size_t)(i - NIN) * 512;
      float4 w = wrow[jc4];
      float cv = hl[ii];
      s.x += cv * w.x; s.y += cv * w.y; s.z += cv * w.z; s.w += cv * w.w;
    }
    ((float4*)part)[bi * 512 + jc4] = s;
  } else if (b < 1152) {
    int bb = b - 128;
    int tn = bb & 31, tk = bb >> 5;
    int r = t >> 4, c = (t & 15) * 4;
#pragma unroll
    for (int i = 0; i < 4; ++i) {
      float4 v = *(const float4*)&Ap[(size_t)(tk * 64 + r + i * 16) * NH + tn * 64 + c];
      ls[r + i * 16][c] = v.x; ls[r + i * 16][c + 1] = v.y;
      ls[r + i * 16][c + 2] = v.z; ls[r + i * 16][c + 3] = v.w;
    }
    __syncthreads();
#pragma unroll
    for (int i = 0; i < 4; ++i) {
      int n = r + i * 16;
      ushort4 o;
      o.x = f2bf(ls[c][n]);     o.y = f2bf(ls[c + 1][n]);
      o.z = f2bf(ls[c + 2][n]); o.w = f2bf(ls[c + 3][n]);
      *(ushort4*)&Bt[(size_t)(tn * 64 + n) * NH + tk * 64 + c] = o;
    }
  } else {
    float* red = (float*)ls;
    float su = 0, sx = 0, sh = 0;
    for (int i = t; i < NU;  i += 256) su += u[i] * u[i];
    for (int i = t; i < NIN; i += 256) sx += x[i] * x[i];
    for (int i = t; i < NH;  i += 256) sh += hprev[i] * hprev[i];
    float r0 = blockReduce256(su, red);
    float r1 = blockReduce256(sx, red);
    float r2 = blockReduce256(sh, red);
    if (t == 0) { nrm[0] = r0; nrm[1] = r1; nrm[2] = r2; }
  }
}

// fused: blocks [0,4096): Abf[m][k] = bf16(dh[m]*W_h[m][k]) with dh recomputed
// per block from 64 z-partials; blocks [4096,4104): z2 epilogue (h_next, dh, dhp).
__global__ void k_prep(const float* __restrict__ Wh, const float* __restrict__ part,
                       const float* __restrict__ bias,
                       unsigned short* __restrict__ Abf,
                       float* __restrict__ outh, float* __restrict__ dh,
                       float* __restrict__ dhp) {
  __shared__ float red[256];
  __shared__ float dhs;
  int b = blockIdx.x, t = threadIdx.x;
  if (b < 4096) {
    int r = b >> 1;                       // 256 float4 per block = half a 512-float4 row
    if (t < 64) red[t] = part[t * NH + r];
    __syncthreads();
    if (t == 0) {
      float z = bias[r];
      for (int i = 0; i < 64; ++i) z += red[i];
      float h = tanhf(z);
      dhs = 1.f - h * h;
    }
    __syncthreads();
    float d = dhs;
    int idx4 = b * 256 + t;               // 4096*256 == 2^20 == Wh/4 exactly
    float4 w = ((const float4*)Wh)[idx4];
    ushort4 o;
    o.x = f2bf(w.x * d); o.y = f2bf(w.y * d);
    o.z = f2bf(w.z * d); o.w = f2bf(w.w * d);
    ((ushort4*)Abf)[idx4] = o;
  } else {
    int j = (b - 4096) * 256 + t;
    float z = bias[j];
    for (int bi = 0; bi < 64; ++bi) z += part[bi * NH + j];
    float h = tanhf(z);
    outh[j] = h;
    float d = 1.f - h * h;
    dh[j] = d;
    float s = blockReduce256(d * d, red);
    if (t == 0) dhp[b - 4096] = s;
  }
}

#define GLOAD_LDS(gsrc, ldst) \
  __builtin_amdgcn_global_load_lds( \
      (const __attribute__((address_space(1))) unsigned int*)(gsrc), \
      (__attribute__((address_space(3))) unsigned int*)(ldst), 16, 0, 0)

// C[m][n] = sum_k Abf[m][k]*Bt[n][k] (= H @ A_prev), writes Hq f32 + sumsq gp.
// PROVEN CORE, byte-identical: 64x64 tile, BK=64, 4 waves, wave subtile 32x32
// (acc[2][2], 8 MFMA/step), 32 stage->drain->compute iters; LDS [row][kg]
// granules XOR'd kg^(row&7) both-sides (0 conflicts measured).
// Grid 1024 -> 4 blocks/CU. Plain stores only -- NO atomics.
__global__ __launch_bounds__(256) void k_gemm(const unsigned short* __restrict__ Abf,
                                              const unsigned short* __restrict__ Bt,
                                              float* __restrict__ Hq,
                                              float* __restrict__ gp) {
  __shared__ unsigned short As[512 * 8];   // 64 rows x 8 granules x 16B = 8KB
  __shared__ unsigned short Bs[512 * 8];
  __shared__ float red[256];
  const int K = NH;
  int t = threadIdx.x;
  int lane = t & 63;
  int bm = blockIdx.x >> 5, bn = blockIdx.x & 31;
  int wid = t >> 6;
  int wr = wid >> 1, wc = wid & 1;

  int srow = t >> 3, skg = t & 7;
  int sxg = skg ^ (srow & 7);
  const unsigned short* AgBase = Abf + (size_t)(bm * 64 + srow) * K + sxg * 8;
  const unsigned short* BgBase = Bt  + (size_t)(bn * 64 + srow) * K + sxg * 8;

  f32x4 acc[2][2] = {};

  for (int k0 = 0; k0 < K; k0 += 64) {
    GLOAD_LDS(AgBase + k0,          As + t * 8);
    GLOAD_LDS(AgBase + 32 * K + k0, As + (t + 256) * 8);
    GLOAD_LDS(BgBase + k0,          Bs + t * 8);
    GLOAD_LDS(BgBase + 32 * K + k0, Bs + (t + 256) * 8);
    __syncthreads();
    __builtin_amdgcn_s_setprio(1);
#pragma unroll
    for (int kk = 0; kk < 2; ++kk) {
      bf16x8 af[2], bfr[2];
#pragma unroll
      for (int mi = 0; mi < 2; ++mi) {
        int row = wr * 32 + mi * 16 + (lane & 15);
        int kg = (kk * 4 + (lane >> 4)) ^ (row & 7);
        af[mi] = *(const bf16x8*)&As[(row * 8 + kg) * 8];
      }
#pragma unroll
      for (int ni = 0; ni < 2; ++ni) {
        int row = wc * 32 + ni * 16 + (lane & 15);
        int kg = (kk * 4 + (lane >> 4)) ^ (row & 7);
        bfr[ni] = *(const bf16x8*)&Bs[(row * 8 + kg) * 8];
      }
#pragma unroll
      for (int mi = 0; mi < 2; ++mi)
#pragma unroll
        for (int ni = 0; ni < 2; ++ni)
          acc[mi][ni] = __builtin_amdgcn_mfma_f32_16x16x32_bf16(af[mi], bfr[ni], acc[mi][ni], 0, 0, 0);
    }
    __builtin_amdgcn_s_setprio(0);
    __syncthreads();
  }

  float ss = 0.f;
  int r0 = bm * 64 + wr * 32 + (lane >> 4) * 4;
  int c0 = bn * 64 + wc * 32 + (lane & 15);
#pragma unroll
  for (int mi = 0; mi < 2; ++mi)
#pragma unroll
    for (int r = 0; r < 4; ++r) {
      int row = r0 + mi * 16 + r;
#pragma unroll
      for (int ni = 0; ni < 2; ++ni) {
        float v = acc[mi][ni][r];
        Hq[(size_t)row * NH + c0 + ni * 16] = v;
        ss += v * v;
      }
    }
  float s = blockReduce256(ss, red);
  if (t == 0) gp[blockIdx.x] = s;
}

// blocks [0,2048): A_next = cf2*Hq (+ diag cf3*dh) in place, float4.
// blocks [2048,2061): u_next.
// Every block re-reduces gp[1024] + dhp + nrm and computes coef inline
// (identical fixed-order arithmetic per block -> deterministic; L2-hot).
__global__ void k_Au(float* __restrict__ Hq, const float* __restrict__ dh,
                     const float* __restrict__ gp, const float* __restrict__ dhp,
                     const float* __restrict__ nrm,
                     const float* __restrict__ u, const float* __restrict__ x,
                     const float* __restrict__ hprev, float* __restrict__ outu) {
  __shared__ float red[256];
  __shared__ float cf[4];
  int t = threadIdx.x;
  float s = blockReduce256(gp[t] + gp[t + 256] + gp[t + 512] + gp[t + 768], red);
  if (t == 0) {
    float sdh = 0;
    for (int i = 0; i < 8; ++i) sdh += dhp[i];
    float nu  = sqrtf(nrm[0]);
    float nhq = sqrtf(nrm[1] + nrm[2] + 1.0f);
    float ndh = sqrtf(sdh);
    float nHq = sqrtf(s);
    float p1 = sqrtf(nHq / (EPSF + nu));
    float p2 = sqrtf(ndh / (EPSF + nhq));
    cf[0] = C1 * p1;
    cf[1] = C2 * p2;
    cf[2] = C1 / (p1 + EPSF);
    cf[3] = C2 / (p2 + EPSF);
  }
  __syncthreads();

  if (blockIdx.x >= 2048) {
    int i = (blockIdx.x - 2048) * 256 + t;
    if (i < NU) {
      float hq = (i < NIN) ? x[i] : (i < NIN + NH ? hprev[i - NIN] : 1.0f);
      outu[i] = cf[0] * u[i] + cf[1] * hq;
    }
    return;
  }
  float sA = cf[2], sD = cf[3];
  float4* H4 = (float4*)Hq;
  // 2048 blocks * 256 thr * 2 iters == 2^20 float4 == NH*NH/4 exactly
  int i4 = blockIdx.x * 256 + t;
#pragma unroll
  for (int it = 0; it < 2; ++it, i4 += 2048 * 256) {
    float4 v = H4[i4];
    v.x *= sA; v.y *= sA; v.z *= sA; v.w *= sA;
    int row = i4 >> 9;                 // 512 float4 per row
    int c = (i4 & 511) * 4;
    int j = row - c;
    if (j >= 0 && j < 4) {
      float add = sD * dh[row];
      if (j == 0) v.x += add; else if (j == 1) v.y += add;
      else if (j == 2) v.z += add; else v.w += add;
    }
    H4[i4] = v;
  }
}

extern "C" void kernel_launch(void* const* d_in, const int* in_sizes, int n_in,
                              void* d_out, int out_size, void* d_ws, size_t ws_size,
                              hipStream_t stream) {
  const float* x     = (const float*)d_in[0];
  const float* hprev = (const float*)d_in[1];
  const float* Win   = (const float*)d_in[2];
  const float* Wh    = (const float*)d_in[3];
  const float* bias  = (const float*)d_in[4];
  const float* uprev = (const float*)d_in[5];
  const float* Ap    = (const float*)d_in[6];

  float* out  = (float*)d_out;
  float* outh = out;                 // [2048]
  float* outu = out + NH;            // [3073]
  float* Hq   = out + NH + NU;       // [2048*2048] (in-place scaled to A_next)
  float* part = Hq;                  // z-partials (512KB) borrow region (dead until k_gemm)

  char* ws = (char*)d_ws;
  float* dh   = (float*)ws;
  float* dhp  = (float*)(ws + 8192);
  float* gp   = (float*)(ws + 8256);
  float* nrm  = (float*)(ws + 12352);
  unsigned short* Abf = (unsigned short*)(ws + 16384);
  unsigned short* Bt  = (unsigned short*)(ws + 8404992);

  k_stage1 <<<1153, 256, 0, stream>>>(x, hprev, Win, Wh, part, Ap, Bt, uprev, nrm);
  k_prep   <<<4104, 256, 0, stream>>>(Wh, part, bias, Abf, outh, dh, dhp);
  k_gemm   <<<1024, 256, 0, stream>>>(Abf, Bt, Hq, gp);
  k_Au     <<<2061, 256, 0, stream>>>(Hq, dh, gp, dhp, nrm, uprev, x, hprev, outu);
}

// Round 14
// 61.131 us; speedup vs baseline: 1.3277x; 1.0683x over previous
//
#include <hip/hip_runtime.h>
#include <hip/hip_bf16.h>
#include <math.h>

// signs c1,c2 decoded in round 0/1: both +1 (absmax 0.0078 = bf16 noise)
#define C1 1.0f
#define C2 1.0f

static constexpr float EPSF = 1e-8f;
static constexpr int NIN = 1024;
static constexpr int NH  = 2048;
static constexpr int NU  = NIN + NH + 1;   // 3073

typedef __attribute__((ext_vector_type(8))) short bf16x8;
typedef __attribute__((ext_vector_type(4))) float f32x4;

// ws layout (bytes) -- MUST stay <= 16809984 (round-1 proven ws budget):
//   0       dh    2048 f32 (8 KiB)
//   8192    dhp   8 f32
//   8256    gp    1024 f32 (4 KiB, gemm grid partials)
//   12352   nrm   3 f32
//   16384   Abf   2048*2048 bf16 (8 MiB) = dh[m]*W_h[m][k]
//   8404992 Bt    2048*2048 bf16 (8 MiB) = A_prev^T
//   end 16793600
// z-partials (64*2048 f32, 512 KiB) live in d_out's A_next region (dead until k_gemm).
//
// LESSON (r8-r10): agent-scope ordered atomics inside k_gemm force L2
// writeback/invalidate -> panels evicted -> gemm 33->104us. NO atomics.
// LESSON (r11-r12): a LOAD inside a data-dependent branch can't be
// speculated/pipelined -> serial chain. Skips must be expressed as a
// compacted index list (ballot+popc), loads unconditional.

__device__ inline unsigned short f2bf(float f) {
  union { float f; unsigned u; } v; v.f = f;
  unsigned r = v.u + 0x7FFFu + ((v.u >> 16) & 1u);   // RNE
  return (unsigned short)(r >> 16);
}

__device__ inline float blockReduce256(float v, float* red) {
  int t = threadIdx.x;
  red[t] = v;
  __syncthreads();
  for (int s = 128; s > 0; s >>= 1) {
    if (t < s) red[t] += red[t + s];
    __syncthreads();
  }
  float r = red[0];
  __syncthreads();
  return r;
}

// fused stage 1 (no z-dependency):
//   blocks [0,128)     : z partials, float4: 64 i-slices (48 rows) x 2 j-halves.
//                        Coefficients prefetched to LDS; wave-0 ballot-compacts
//                        NONZERO coefficient indices -> loop over compact list
//                        with unconditional loads (all-zero h_prev slices do
//                        zero W_h loads; correct for arbitrary inputs).
//   blocks [128,1152)  : Bt[n][k] = bf16(A_prev[k][n]) 64x64 tiled transpose
//   block  1152        : norms (sumsq u, x, h_prev)
__global__ void k_stage1(const float* __restrict__ x, const float* __restrict__ hprev,
                         const float* __restrict__ Win, const float* __restrict__ Wh,
                         float* __restrict__ part,
                         const float* __restrict__ Ap, unsigned short* __restrict__ Bt,
                         const float* __restrict__ u, float* __restrict__ nrm) {
  __shared__ float ls[64][65];
  __shared__ float hl[48];
  __shared__ int   idxl[48];
  __shared__ int   cntS;
  int b = blockIdx.x;
  int t = threadIdx.x;
  if (b < 128) {
    int bj = b & 1, bi = b >> 1;
    int jc4 = bj * 256 + t;             // float4 column-group (0..511)
    int i0 = bi * 48;                   // 64*48 == 3072 == NIN+NH exactly
    if (t < 48) {
      int i = i0 + t;
      hl[t] = (i < NIN) ? x[i] : hprev[i - NIN];   // 48 parallel loads
    }
    __syncthreads();
    if (t < 64) {                       // wave 0 compacts nonzero coefficients
      bool nz = (t < 48) && (hl[t] != 0.0f);
      unsigned long long mask = __ballot(nz);
      if (nz) {
        int pos = __popcll(mask & ((1ull << t) - 1ull));
        idxl[pos] = t;
      }
      if (t == 0) cntS = __popcll(mask);
    }
    __syncthreads();
    int cnt = cntS;                     // block-uniform loop bound
    float4 s = {0.f, 0.f, 0.f, 0.f};
    for (int ii = 0; ii < cnt; ++ii) {
      int rl = idxl[ii];
      int i = i0 + rl;
      // branch selects pointer only; the load below is UNCONDITIONAL
      const float4* wrow = (i < NIN)
        ? (const float4*)Win + (size_t)i * 512
        : (const float4*)Wh  + (size_t)(i - NIN) * 512;
      float4 w = wrow[jc4];
      float cv = hl[rl];
      s.x += cv * w.x; s.y += cv * w.y; s.z += cv * w.z; s.w += cv * w.w;
    }
    ((float4*)part)[bi * 512 + jc4] = s;
  } else if (b < 1152) {
    int bb = b - 128;
    int tn = bb & 31, tk = bb >> 5;
    int r = t >> 4, c = (t & 15) * 4;
#pragma unroll
    for (int i = 0; i < 4; ++i) {
      float4 v = *(const float4*)&Ap[(size_t)(tk * 64 + r + i * 16) * NH + tn * 64 + c];
      ls[r + i * 16][c] = v.x; ls[r + i * 16][c + 1] = v.y;
      ls[r + i * 16][c + 2] = v.z; ls[r + i * 16][c + 3] = v.w;
    }
    __syncthreads();
#pragma unroll
    for (int i = 0; i < 4; ++i) {
      int n = r + i * 16;
      ushort4 o;
      o.x = f2bf(ls[c][n]);     o.y = f2bf(ls[c + 1][n]);
      o.z = f2bf(ls[c + 2][n]); o.w = f2bf(ls[c + 3][n]);
      *(ushort4*)&Bt[(size_t)(tn * 64 + n) * NH + tk * 64 + c] = o;
    }
  } else {
    float* red = (float*)ls;
    float su = 0, sx = 0, sh = 0;
    for (int i = t; i < NU;  i += 256) su += u[i] * u[i];
    for (int i = t; i < NIN; i += 256) sx += x[i] * x[i];
    for (int i = t; i < NH;  i += 256) sh += hprev[i] * hprev[i];
    float r0 = blockReduce256(su, red);
    float r1 = blockReduce256(sx, red);
    float r2 = blockReduce256(sh, red);
    if (t == 0) { nrm[0] = r0; nrm[1] = r1; nrm[2] = r2; }
  }
}

// fused: blocks [0,4096): Abf[m][k] = bf16(dh[m]*W_h[m][k]) with dh recomputed
// per block from 64 z-partials; blocks [4096,4104): z2 epilogue (h_next, dh, dhp).
__global__ void k_prep(const float* __restrict__ Wh, const float* __restrict__ part,
                       const float* __restrict__ bias,
                       unsigned short* __restrict__ Abf,
                       float* __restrict__ outh, float* __restrict__ dh,
                       float* __restrict__ dhp) {
  __shared__ float red[256];
  __shared__ float dhs;
  int b = blockIdx.x, t = threadIdx.x;
  if (b < 4096) {
    int r = b >> 1;                       // 256 float4 per block = half a 512-float4 row
    if (t < 64) red[t] = part[t * NH + r];
    __syncthreads();
    if (t == 0) {
      float z = bias[r];
      for (int i = 0; i < 64; ++i) z += red[i];
      float h = tanhf(z);
      dhs = 1.f - h * h;
    }
    __syncthreads();
    float d = dhs;
    int idx4 = b * 256 + t;               // 4096*256 == 2^20 == Wh/4 exactly
    float4 w = ((const float4*)Wh)[idx4];
    ushort4 o;
    o.x = f2bf(w.x * d); o.y = f2bf(w.y * d);
    o.z = f2bf(w.z * d); o.w = f2bf(w.w * d);
    ((ushort4*)Abf)[idx4] = o;
  } else {
    int j = (b - 4096) * 256 + t;
    float z = bias[j];
    for (int bi = 0; bi < 64; ++bi) z += part[bi * NH + j];
    float h = tanhf(z);
    outh[j] = h;
    float d = 1.f - h * h;
    dh[j] = d;
    float s = blockReduce256(d * d, red);
    if (t == 0) dhp[b - 4096] = s;
  }
}

#define GLOAD_LDS(gsrc, ldst) \
  __builtin_amdgcn_global_load_lds( \
      (const __attribute__((address_space(1))) unsigned int*)(gsrc), \
      (__attribute__((address_space(3))) unsigned int*)(ldst), 16, 0, 0)

// C[m][n] = sum_k Abf[m][k]*Bt[n][k] (= H @ A_prev), writes Hq f32 + sumsq gp.
// PROVEN CORE: 64x64 tile, BK=64, 4 waves, wave subtile 32x32 (acc[2][2],
// 8 MFMA/step), 32 stage->drain->compute iters; LDS [row][kg] granules XOR'd
// kg^(row&7) both-sides (0 conflicts measured). Grid 1024 -> 4 blocks/CU.
// NEW: XCD-aware bid swizzle (T1; 1024%8==0 -> bijective). HW dispatches
// bid -> XCD bid%8; swz groups each XCD onto bm in [4x,4x+4) x all bn:
// its 4 A-panels (1MB) go L2-resident, B k-window slides in L2 -> staging
// loads become L2 hits instead of L3, shortening the per-step vmcnt drain.
__global__ __launch_bounds__(256) void k_gemm(const unsigned short* __restrict__ Abf,
                                              const unsigned short* __restrict__ Bt,
                                              float* __restrict__ Hq,
                                              float* __restrict__ gp) {
  __shared__ unsigned short As[512 * 8];   // 64 rows x 8 granules x 16B = 8KB
  __shared__ unsigned short Bs[512 * 8];
  __shared__ float red[256];
  const int K = NH;
  int t = threadIdx.x;
  int lane = t & 63;
  int bid = blockIdx.x;
  int swz = (bid & 7) * 128 + (bid >> 3);   // XCD-chunked, bijective on [0,1024)
  int bm = swz >> 5, bn = swz & 31;
  int wid = t >> 6;
  int wr = wid >> 1, wc = wid & 1;

  int srow = t >> 3, skg = t & 7;
  int sxg = skg ^ (srow & 7);
  const unsigned short* AgBase = Abf + (size_t)(bm * 64 + srow) * K + sxg * 8;
  const unsigned short* BgBase = Bt  + (size_t)(bn * 64 + srow) * K + sxg * 8;

  f32x4 acc[2][2] = {};

  for (int k0 = 0; k0 < K; k0 += 64) {
    GLOAD_LDS(AgBase + k0,          As + t * 8);
    GLOAD_LDS(AgBase + 32 * K + k0, As + (t + 256) * 8);
    GLOAD_LDS(BgBase + k0,          Bs + t * 8);
    GLOAD_LDS(BgBase + 32 * K + k0, Bs + (t + 256) * 8);
    __syncthreads();
    __builtin_amdgcn_s_setprio(1);
#pragma unroll
    for (int kk = 0; kk < 2; ++kk) {
      bf16x8 af[2], bfr[2];
#pragma unroll
      for (int mi = 0; mi < 2; ++mi) {
        int row = wr * 32 + mi * 16 + (lane & 15);
        int kg = (kk * 4 + (lane >> 4)) ^ (row & 7);
        af[mi] = *(const bf16x8*)&As[(row * 8 + kg) * 8];
      }
#pragma unroll
      for (int ni = 0; ni < 2; ++ni) {
        int row = wc * 32 + ni * 16 + (lane & 15);
        int kg = (kk * 4 + (lane >> 4)) ^ (row & 7);
        bfr[ni] = *(const bf16x8*)&Bs[(row * 8 + kg) * 8];
      }
#pragma unroll
      for (int mi = 0; mi < 2; ++mi)
#pragma unroll
        for (int ni = 0; ni < 2; ++ni)
          acc[mi][ni] = __builtin_amdgcn_mfma_f32_16x16x32_bf16(af[mi], bfr[ni], acc[mi][ni], 0, 0, 0);
    }
    __builtin_amdgcn_s_setprio(0);
    __syncthreads();
  }

  float ss = 0.f;
  int r0 = bm * 64 + wr * 32 + (lane >> 4) * 4;
  int c0 = bn * 64 + wc * 32 + (lane & 15);
#pragma unroll
  for (int mi = 0; mi < 2; ++mi)
#pragma unroll
    for (int r = 0; r < 4; ++r) {
      int row = r0 + mi * 16 + r;
#pragma unroll
      for (int ni = 0; ni < 2; ++ni) {
        float v = acc[mi][ni][r];
        Hq[(size_t)row * NH + c0 + ni * 16] = v;
        ss += v * v;
      }
    }
  float s = blockReduce256(ss, red);
  if (t == 0) gp[blockIdx.x] = s;
}

// blocks [0,2048): A_next = cf2*Hq (+ diag cf3*dh) in place, float4.
// blocks [2048,2061): u_next.
// Every block re-reduces gp[1024] + dhp + nrm and computes coef inline
// (identical fixed-order arithmetic per block -> deterministic; L2-hot).
__global__ void k_Au(float* __restrict__ Hq, const float* __restrict__ dh,
                     const float* __restrict__ gp, const float* __restrict__ dhp,
                     const float* __restrict__ nrm,
                     const float* __restrict__ u, const float* __restrict__ x,
                     const float* __restrict__ hprev, float* __restrict__ outu) {
  __shared__ float red[256];
  __shared__ float cf[4];
  int t = threadIdx.x;
  float s = blockReduce256(gp[t] + gp[t + 256] + gp[t + 512] + gp[t + 768], red);
  if (t == 0) {
    float sdh = 0;
    for (int i = 0; i < 8; ++i) sdh += dhp[i];
    float nu  = sqrtf(nrm[0]);
    float nhq = sqrtf(nrm[1] + nrm[2] + 1.0f);
    float ndh = sqrtf(sdh);
    float nHq = sqrtf(s);
    float p1 = sqrtf(nHq / (EPSF + nu));
    float p2 = sqrtf(ndh / (EPSF + nhq));
    cf[0] = C1 * p1;
    cf[1] = C2 * p2;
    cf[2] = C1 / (p1 + EPSF);
    cf[3] = C2 / (p2 + EPSF);
  }
  __syncthreads();

  if (blockIdx.x >= 2048) {
    int i = (blockIdx.x - 2048) * 256 + t;
    if (i < NU) {
      float hq = (i < NIN) ? x[i] : (i < NIN + NH ? hprev[i - NIN] : 1.0f);
      outu[i] = cf[0] * u[i] + cf[1] * hq;
    }
    return;
  }
  float sA = cf[2], sD = cf[3];
  float4* H4 = (float4*)Hq;
  // 2048 blocks * 256 thr * 2 iters == 2^20 float4 == NH*NH/4 exactly
  int i4 = blockIdx.x * 256 + t;
#pragma unroll
  for (int it = 0; it < 2; ++it, i4 += 2048 * 256) {
    float4 v = H4[i4];
    v.x *= sA; v.y *= sA; v.z *= sA; v.w *= sA;
    int row = i4 >> 9;                 // 512 float4 per row
    int c = (i4 & 511) * 4;
    int j = row - c;
    if (j >= 0 && j < 4) {
      float add = sD * dh[row];
      if (j == 0) v.x += add; else if (j == 1) v.y += add;
      else if (j == 2) v.z += add; else v.w += add;
    }
    H4[i4] = v;
  }
}

extern "C" void kernel_launch(void* const* d_in, const int* in_sizes, int n_in,
                              void* d_out, int out_size, void* d_ws, size_t ws_size,
                              hipStream_t stream) {
  const float* x     = (const float*)d_in[0];
  const float* hprev = (const float*)d_in[1];
  const float* Win   = (const float*)d_in[2];
  const float* Wh    = (const float*)d_in[3];
  const float* bias  = (const float*)d_in[4];
  const float* uprev = (const float*)d_in[5];
  const float* Ap    = (const float*)d_in[6];

  float* out  = (float*)d_out;
  float* outh = out;                 // [2048]
  float* outu = out + NH;            // [3073]
  float* Hq   = out + NH + NU;       // [2048*2048] (in-place scaled to A_next)
  float* part = Hq;                  // z-partials (512KB) borrow region (dead until k_gemm)

  char* ws = (char*)d_ws;
  float* dh   = (float*)ws;
  float* dhp  = (float*)(ws + 8192);
  float* gp   = (float*)(ws + 8256);
  float* nrm  = (float*)(ws + 12352);
  unsigned short* Abf = (unsigned short*)(ws + 16384);
  unsigned short* Bt  = (unsigned short*)(ws + 8404992);

  k_stage1 <<<1153, 256, 0, stream>>>(x, hprev, Win, Wh, part, Ap, Bt, uprev, nrm);
  k_prep   <<<4104, 256, 0, stream>>>(Wh, part, bias, Abf, outh, dh, dhp);
  k_gemm   <<<1024, 256, 0, stream>>>(Abf, Bt, Hq, gp);
  k_Au     <<<2061, 256, 0, stream>>>(Hq, dh, gp, dhp, nrm, uprev, x, hprev, outu);
}